// Round 7
// baseline (226.330 us; speedup 1.0000x reference)
//
#include <hip/hip_runtime.h>
#include <cmath>

namespace {

using bf16x8 = __attribute__((ext_vector_type(8))) short;
using f32x4  = __attribute__((ext_vector_type(4))) float;

constexpr int NT = 192;        // 3 waves per block
constexpr int NS = 16;         // samples per block (one MFMA M-tile)
constexpr int TILE_BYTES = NS * 31 * 32 * 2;  // 31744 B (LPAD=31)
constexpr int B = 16384;

__device__ __forceinline__ short f2bf(float f) {  // RNE float->bf16
  unsigned u = __float_as_uint(f);
  return (short)((u + 0x7FFFu + ((u >> 16) & 1u)) >> 16);
}

// Granule index for tile[s][q][cq*8..+7]. Bijective: only permutes cq within
// the (s,q) quad (blocks 4u..4u+3 disjoint). Proven correct+fast in round 3.
__device__ __forceinline__ int gidx(int s, int q, int cq) {
  return (s * 31 + q) * 4 + ((cq ^ ((s >> 1) + (q >> 1))) & 3);
}

__device__ __forceinline__ bf16x8 ldcol(const char* smem, int s, int cq, int q) {
  return *(const bf16x8*)(smem + (gidx(s, q, cq) << 4));
}

// One wave-role: kernel sizes K1 (and optional nested K2 < K1). Runtime i,L.
// Weight fragments rebuilt in-register from f32 global (L2-resident, r3 path
// — do NOT read weights from d_ws: workspace reads go to HBM uncached).
template<int K1, int K2>
__device__ __forceinline__ void run_role(
    const char* __restrict__ smem, int s, int cq, int f,
    const float* __restrict__ wk1, const float* __restrict__ ck1,
    const float* __restrict__ wk2, const float* __restrict__ ck2,
    const float* __restrict__ dw, int i, int L, f32x4& dvec)
{
  constexpr int KK1 = (K1 - 1) / 2;
  constexpr int KK2 = (K2 > 0) ? (K2 - 1) / 2 : 0;
  constexpr int NCH = (K1 >= 7) ? 3 : 2;   // accumulator chains (ILP)

  // B-operand fragments: lane = filter f, holds w[f][cq*8+j][t], j=0..7.
  bf16x8 wf1[K1];
  #pragma unroll
  for (int t = 0; t < K1; ++t) {
    const float* wp = wk1 + (size_t)((i * 16 + f) * 32 + cq * 8) * K1 + t;
    bf16x8 v;
    #pragma unroll
    for (int j = 0; j < 8; ++j) v[j] = f2bf(wp[(size_t)j * K1]);
    wf1[t] = v;
  }
  bf16x8 wf2[(K2 > 0) ? K2 : 1];
  if constexpr (K2 > 0) {
    #pragma unroll
    for (int t = 0; t < K2; ++t) {
      const float* wp = wk2 + (size_t)((i * 16 + f) * 32 + cq * 8) * K2 + t;
      bf16x8 v;
      #pragma unroll
      for (int j = 0; j < 8; ++j) v[j] = f2bf(wp[(size_t)j * K2]);
      wf2[t] = v;
    }
  }

  const float b1 = ck1[i * 16 + f];
  float b2 = 0.f;
  if constexpr (K2 > 0) b2 = ck2[i * 16 + f];

  f32x4 mx1 = {0.f, 0.f, 0.f, 0.f};   // ReLU folded into max-init 0
  f32x4 mx2 = {0.f, 0.f, 0.f, 0.f};

  // Sliding window invariant: af[(P+t)%K1] holds padded col P + 4 - KK1 + t.
  bf16x8 af[K1];
  #pragma unroll
  for (int j = 0; j < K1; ++j) af[j] = ldcol(smem, s, cq, 4 - KK1 + j);

  auto body = [&](int p, int pi) {
    f32x4 ca = {b1, b1, b1, b1};      // chain 0 (bias pre-added)
    f32x4 cb = {0.f, 0.f, 0.f, 0.f};  // chain 1
    f32x4 cc = {0.f, 0.f, 0.f, 0.f};  // chain 2 (K1>=7 only)
    #pragma unroll
    for (int t = 0; t < K1; ++t) {
      const int m = t % NCH;          // compile-time in unrolled loop
      if (m == 0)
        ca = __builtin_amdgcn_mfma_f32_16x16x32_bf16(af[(pi + t) % K1], wf1[t], ca, 0, 0, 0);
      else if (m == 1)
        cb = __builtin_amdgcn_mfma_f32_16x16x32_bf16(af[(pi + t) % K1], wf1[t], cb, 0, 0, 0);
      else
        cc = __builtin_amdgcn_mfma_f32_16x16x32_bf16(af[(pi + t) % K1], wf1[t], cc, 0, 0, 0);
    }
    if constexpr (K2 > 0) {
      f32x4 cd = {b2, b2, b2, b2};
      #pragma unroll
      for (int t = 0; t < K2; ++t)
        cd = __builtin_amdgcn_mfma_f32_16x16x32_bf16(af[(pi + (KK1 - KK2) + t) % K1], wf2[t], cd, 0, 0, 0);
      #pragma unroll
      for (int r = 0; r < 4; ++r) mx2[r] = fmaxf(mx2[r], cd[r]);
    }
    #pragma unroll
    for (int r = 0; r < 4; ++r) {
      float tot = ca[r] + cb[r];
      if constexpr (NCH == 3) tot += cc[r];
      mx1[r] = fmaxf(mx1[r], tot);
    }
    if (p + pi + 1 < L)                         // slide: col for position p+pi+1
      af[pi] = ldcol(smem, s, cq, p + pi + 5 + KK1);
  };

  int p = 0;
  for (; p + K1 <= L; p += K1) {                // K1-blocked -> static rotation idx
    #pragma unroll
    for (int pi = 0; pi < K1; ++pi) body(p, pi);
  }
  #pragma unroll
  for (int pi = 0; pi < K1 - 1; ++pi)           // tail (rem <= K1-1)
    if (p + pi < L) body(p, pi);

  {
    const float dv1 = dw[(i * 5 + KK1) * 16 + f];
    #pragma unroll
    for (int r = 0; r < 4; ++r) dvec[r] = fmaf(mx1[r], dv1, dvec[r]);
  }
  if constexpr (K2 > 0) {
    const float dv2 = dw[(i * 5 + KK2) * 16 + f];
    #pragma unroll
    for (int r = 0; r < 4; ++r) dvec[r] = fmaf(mx2[r], dv2, dvec[r]);
  }
}

// ---- main: grid 2048; blockIdx = tile*2 + half; half 0 -> inputs {0,3,5},
// half 1 -> {1,2,4,6}; pre-sigmoid partial dot written to ws. ----
__global__ __launch_bounds__(NT, 3) void nettcr_mfma(
    const float* __restrict__ x0, const float* __restrict__ x1,
    const float* __restrict__ x2, const float* __restrict__ x3,
    const float* __restrict__ x4, const float* __restrict__ x5,
    const float* __restrict__ x6,
    const float* __restrict__ w1, const float* __restrict__ c1,
    const float* __restrict__ w3, const float* __restrict__ c3,
    const float* __restrict__ w5, const float* __restrict__ c5,
    const float* __restrict__ w7, const float* __restrict__ c7,
    const float* __restrict__ w9, const float* __restrict__ c9,
    const float* __restrict__ dw,
    float* __restrict__ part)
{
  __shared__ __align__(16) char smem[TILE_BYTES];
  const int tid  = threadIdx.x;
  const int lane = tid & 63;
  const int wid  = tid >> 6;
  const int h    = blockIdx.x & 1;
  const int b0   = (blockIdx.x >> 1) * NS;
  const int s    = lane & 15;      // A-side: sample row
  const int cq   = lane >> 4;      // k-quadrant: channels cq*8..+7
  const int f    = lane & 15;      // B-side: filter col

  f32x4 dvec = {0.f, 0.f, 0.f, 0.f};

  const int nin = h ? 4 : 3;
  for (int j = 0; j < nin; ++j) {
    const float* xi; int i, L;
    if (h == 0) {
      switch (j) {
        case 0:  i = 0; xi = x0; L = 12; break;
        case 1:  i = 3; xi = x3; L = 22; break;
        default: i = 5; xi = x5; L = 7;  break;
      }
    } else {
      switch (j) {
        case 0:  i = 1; xi = x1; L = 7;  break;
        case 1:  i = 2; xi = x2; L = 8;  break;
        case 2:  i = 4; xi = x4; L = 6;  break;
        default: i = 6; xi = x6; L = 23; break;
      }
    }
    __syncthreads();   // all waves done reading previous tile
    // stage: x[b0+ss][c][l] (f32) -> tile[ss][l+4][c] (bf16), swizzled writes
    for (int e = tid; e < 64 * L; e += NT) {
      const int l  = e % L;
      const int rr = e / L;
      const int cg = rr & 3;
      const int ss = rr >> 2;
      const float* src = xi + ((size_t)(b0 + ss) * 32 + cg * 8) * L + l;
      bf16x8 pk;
      #pragma unroll
      for (int jj = 0; jj < 8; ++jj) pk[jj] = f2bf(src[(size_t)jj * L]);
      *(bf16x8*)(smem + (gidx(ss, l + 4, cg) << 4)) = pk;
    }
    // zero the 4+4 SAME-padding columns (branchless taps)
    for (int e = tid; e < 512; e += NT) {
      const int q8 = e & 7;
      const int q  = (q8 < 4) ? q8 : (L + q8);
      const int cg = (e >> 3) & 3;
      const int ss = e >> 5;
      bf16x8 z = {0, 0, 0, 0, 0, 0, 0, 0};
      *(bf16x8*)(smem + (gidx(ss, q, cg) << 4)) = z;
    }
    __syncthreads();   // tile ready

    if (wid == 0)
      run_role<9, 0>(smem, s, cq, f, w9, c9, nullptr, nullptr, dw, i, L, dvec);
    else if (wid == 1)
      run_role<7, 1>(smem, s, cq, f, w7, c7, w1, c1, dw, i, L, dvec);
    else
      run_role<5, 3>(smem, s, cq, f, w5, c5, w3, c3, dw, i, L, dvec);
  }

  // reduce dot partials over 3 waves x 16 filters  (D row = (lane>>4)*4 + r)
  __syncthreads();
  float* red = (float*)smem;
  *(f32x4*)&red[(wid * 64 + lane) * 4] = dvec;
  __syncthreads();
  if (tid < 16) {
    float sum = 0.f;
    const int g4 = tid >> 2, r = tid & 3;
    for (int w = 0; w < 3; ++w)
      #pragma unroll
      for (int f2 = 0; f2 < 16; ++f2)
        sum += red[(w * 64 + g4 * 16 + f2) * 4 + r];
    part[h * B + b0 + tid] = sum;    // pre-sigmoid partial (no db)
  }
}

__global__ void combine_sigmoid(const float* __restrict__ part,
                                const float* __restrict__ db,
                                float* __restrict__ out)
{
  const int i = blockIdx.x * blockDim.x + threadIdx.x;
  if (i < B) {
    const float sum = part[i] + part[B + i] + db[0];
    out[i] = 1.0f / (1.0f + expf(-sum));
  }
}

} // namespace

extern "C" void kernel_launch(void* const* d_in, const int* in_sizes, int n_in,
                              void* d_out, int out_size, void* d_ws, size_t ws_size,
                              hipStream_t stream) {
  (void)ws_size; (void)out_size;
  const float* xs[7];
  for (int i = 0; i < 7; ++i) xs[i] = (const float*)d_in[i];

  const float* wptr[5] = {nullptr, nullptr, nullptr, nullptr, nullptr};
  const float* cptr[5] = {nullptr, nullptr, nullptr, nullptr, nullptr};
  const float* dw = nullptr;
  const float* db = nullptr;
  int c_seen = 0;
  for (int idx = 7; idx < n_in; ++idx) {
    const int sz = in_sizes[idx];
    const float* p = (const float*)d_in[idx];
    if (sz == 1) { db = p; }
    else if (sz == 16 * 35) { dw = p; }                 // 560
    else if (sz == 7 * 16) { cptr[c_seen++] = p; }      // 112, appear in k order
    else {
      const int k = sz / (7 * 16 * 32);                 // 1,3,5,7,9
      wptr[(k - 1) / 2] = p;
    }
  }

  float* part = (float*)d_ws;   // 2*B floats = 128 KB (only per-block partials)

  dim3 grid(2 * (B / NS)), block(NT);
  hipLaunchKernelGGL(nettcr_mfma, grid, block, 0, stream,
                     xs[0], xs[1], xs[2], xs[3], xs[4], xs[5], xs[6],
                     wptr[0], cptr[0], wptr[1], cptr[1], wptr[2], cptr[2],
                     wptr[3], cptr[3], wptr[4], cptr[4], dw, part);

  hipLaunchKernelGGL(combine_sigmoid, dim3((B + 255) / 256), dim3(256), 0, stream,
                     part, db, (float*)d_out);
}

// Round 8
// 185.125 us; speedup vs baseline: 1.2226x; 1.2226x over previous
//
#include <hip/hip_runtime.h>
#include <cmath>

namespace {

using bf16x8 = __attribute__((ext_vector_type(8))) short;
using f32x4  = __attribute__((ext_vector_type(4))) float;

constexpr int NT = 192;        // 3 waves per block
constexpr int NS = 16;         // samples per block (one MFMA M-tile)
constexpr int TILE_BYTES = NS * 31 * 32 * 2;  // 31744 B (LPAD=31)
constexpr int B = 16384;

__device__ __forceinline__ short f2bf(float f) {  // RNE float->bf16
  unsigned u = __float_as_uint(f);
  return (short)((u + 0x7FFFu + ((u >> 16) & 1u)) >> 16);
}

// Granule index for tile[s][q][cq*8..+7]. Bijective: only permutes cq within
// the (s,q) quad (blocks 4u..4u+3 disjoint). Proven correct+fast in round 3.
__device__ __forceinline__ int gidx(int s, int q, int cq) {
  return (s * 31 + q) * 4 + ((cq ^ ((s >> 1) + (q >> 1))) & 3);
}

__device__ __forceinline__ bf16x8 ldcol(const char* smem, int s, int cq, int q) {
  return *(const bf16x8*)(smem + (gidx(s, q, cq) << 4));
}

// One wave-role: kernel sizes K1 (and optional nested K2 < K1). Runtime i,L.
template<int K1, int K2>
__device__ __forceinline__ void run_role(
    const char* __restrict__ smem, int s, int cq, int f,
    const float* __restrict__ wk1, const float* __restrict__ ck1,
    const float* __restrict__ wk2, const float* __restrict__ ck2,
    const float* __restrict__ dw, int i, int L, f32x4& dvec)
{
  constexpr int KK1 = (K1 - 1) / 2;
  constexpr int KK2 = (K2 > 0) ? (K2 - 1) / 2 : 0;
  constexpr int NCH = (K1 >= 7) ? 3 : 2;   // accumulator chains (ILP)

  // B-operand fragments: lane = filter f, holds w[f][cq*8+j][t], j=0..7.
  bf16x8 wf1[K1];
  #pragma unroll
  for (int t = 0; t < K1; ++t) {
    const float* wp = wk1 + (size_t)((i * 16 + f) * 32 + cq * 8) * K1 + t;
    bf16x8 v;
    #pragma unroll
    for (int j = 0; j < 8; ++j) v[j] = f2bf(wp[(size_t)j * K1]);
    wf1[t] = v;
  }
  bf16x8 wf2[(K2 > 0) ? K2 : 1];
  if constexpr (K2 > 0) {
    #pragma unroll
    for (int t = 0; t < K2; ++t) {
      const float* wp = wk2 + (size_t)((i * 16 + f) * 32 + cq * 8) * K2 + t;
      bf16x8 v;
      #pragma unroll
      for (int j = 0; j < 8; ++j) v[j] = f2bf(wp[(size_t)j * K2]);
      wf2[t] = v;
    }
  }

  const float b1 = ck1[i * 16 + f];
  float b2 = 0.f;
  if constexpr (K2 > 0) b2 = ck2[i * 16 + f];

  f32x4 mx1 = {0.f, 0.f, 0.f, 0.f};   // ReLU folded into max-init 0
  f32x4 mx2 = {0.f, 0.f, 0.f, 0.f};

  // Sliding window invariant: af[(P+t)%K1] holds padded col P + 4 - KK1 + t.
  bf16x8 af[K1];
  #pragma unroll
  for (int j = 0; j < K1; ++j) af[j] = ldcol(smem, s, cq, 4 - KK1 + j);

  auto body = [&](int p, int pi) {
    f32x4 ca = {b1, b1, b1, b1};      // chain 0 (bias pre-added)
    f32x4 cb = {0.f, 0.f, 0.f, 0.f};  // chain 1
    f32x4 cc = {0.f, 0.f, 0.f, 0.f};  // chain 2 (K1>=7 only)
    #pragma unroll
    for (int t = 0; t < K1; ++t) {
      const int m = t % NCH;          // compile-time in unrolled loop
      if (m == 0)
        ca = __builtin_amdgcn_mfma_f32_16x16x32_bf16(af[(pi + t) % K1], wf1[t], ca, 0, 0, 0);
      else if (m == 1)
        cb = __builtin_amdgcn_mfma_f32_16x16x32_bf16(af[(pi + t) % K1], wf1[t], cb, 0, 0, 0);
      else
        cc = __builtin_amdgcn_mfma_f32_16x16x32_bf16(af[(pi + t) % K1], wf1[t], cc, 0, 0, 0);
    }
    if constexpr (K2 > 0) {
      f32x4 cd = {b2, b2, b2, b2};
      #pragma unroll
      for (int t = 0; t < K2; ++t)
        cd = __builtin_amdgcn_mfma_f32_16x16x32_bf16(af[(pi + (KK1 - KK2) + t) % K1], wf2[t], cd, 0, 0, 0);
      #pragma unroll
      for (int r = 0; r < 4; ++r) mx2[r] = fmaxf(mx2[r], cd[r]);
    }
    #pragma unroll
    for (int r = 0; r < 4; ++r) {
      float tot = ca[r] + cb[r];
      if constexpr (NCH == 3) tot += cc[r];
      mx1[r] = fmaxf(mx1[r], tot);
    }
    if (p + pi + 1 < L)                         // slide: col for position p+pi+1
      af[pi] = ldcol(smem, s, cq, p + pi + 5 + KK1);
  };

  int p = 0;
  for (; p + K1 <= L; p += K1) {                // K1-blocked -> static rotation idx
    #pragma unroll
    for (int pi = 0; pi < K1; ++pi) body(p, pi);
  }
  #pragma unroll
  for (int pi = 0; pi < K1 - 1; ++pi)           // tail (rem <= K1-1)
    if (p + pi < L) body(p, pi);

  {
    const float dv1 = dw[(i * 5 + KK1) * 16 + f];
    #pragma unroll
    for (int r = 0; r < 4; ++r) dvec[r] = fmaf(mx1[r], dv1, dvec[r]);
  }
  if constexpr (K2 > 0) {
    const float dv2 = dw[(i * 5 + KK2) * 16 + f];
    #pragma unroll
    for (int r = 0; r < 4; ++r) dvec[r] = fmaf(mx2[r], dv2, dvec[r]);
  }
}

// ---- main: grid 2048; blockIdx = tile*2 + half; half 0 -> inputs {0,3,5},
// half 1 -> {1,2,4,6}; pre-sigmoid partial dot written to ws.
// NOTE: no occupancy arg in launch_bounds — (192,3)/(192,4) forced VGPR caps
// of 84/64 and the ~110-130-reg live set spilled to scratch every round
// (the 200-600 MB mystery WRITE_SIZE). Let the allocator size freely.
__global__ __launch_bounds__(NT) void nettcr_mfma(
    const float* __restrict__ x0, const float* __restrict__ x1,
    const float* __restrict__ x2, const float* __restrict__ x3,
    const float* __restrict__ x4, const float* __restrict__ x5,
    const float* __restrict__ x6,
    const float* __restrict__ w1, const float* __restrict__ c1,
    const float* __restrict__ w3, const float* __restrict__ c3,
    const float* __restrict__ w5, const float* __restrict__ c5,
    const float* __restrict__ w7, const float* __restrict__ c7,
    const float* __restrict__ w9, const float* __restrict__ c9,
    const float* __restrict__ dw,
    float* __restrict__ part)
{
  __shared__ __align__(16) char smem[TILE_BYTES];
  const int tid  = threadIdx.x;
  const int lane = tid & 63;
  const int wid  = tid >> 6;
  const int h    = blockIdx.x & 1;
  const int b0   = (blockIdx.x >> 1) * NS;
  const int s    = lane & 15;      // A-side: sample row
  const int cq   = lane >> 4;      // k-quadrant: channels cq*8..+7
  const int f    = lane & 15;      // B-side: filter col

  f32x4 dvec = {0.f, 0.f, 0.f, 0.f};

  const int nin = h ? 4 : 3;
  for (int j = 0; j < nin; ++j) {
    const float* xi; int i, L;
    if (h == 0) {
      switch (j) {
        case 0:  i = 0; xi = x0; L = 12; break;
        case 1:  i = 3; xi = x3; L = 22; break;
        default: i = 5; xi = x5; L = 7;  break;
      }
    } else {
      switch (j) {
        case 0:  i = 1; xi = x1; L = 7;  break;
        case 1:  i = 2; xi = x2; L = 8;  break;
        case 2:  i = 4; xi = x4; L = 6;  break;
        default: i = 6; xi = x6; L = 23; break;
      }
    }
    __syncthreads();   // all waves done reading previous tile
    // stage: x[b0+ss][c][l] (f32) -> tile[ss][l+4][c] (bf16), swizzled writes
    for (int e = tid; e < 64 * L; e += NT) {
      const int l  = e % L;
      const int rr = e / L;
      const int cg = rr & 3;
      const int ss = rr >> 2;
      const float* src = xi + ((size_t)(b0 + ss) * 32 + cg * 8) * L + l;
      bf16x8 pk;
      #pragma unroll
      for (int jj = 0; jj < 8; ++jj) pk[jj] = f2bf(src[(size_t)jj * L]);
      *(bf16x8*)(smem + (gidx(ss, l + 4, cg) << 4)) = pk;
    }
    // zero the 4+4 SAME-padding columns (branchless taps)
    for (int e = tid; e < 512; e += NT) {
      const int q8 = e & 7;
      const int q  = (q8 < 4) ? q8 : (L + q8);
      const int cg = (e >> 3) & 3;
      const int ss = e >> 5;
      bf16x8 z = {0, 0, 0, 0, 0, 0, 0, 0};
      *(bf16x8*)(smem + (gidx(ss, q, cg) << 4)) = z;
    }
    __syncthreads();   // tile ready

    if (wid == 0)
      run_role<9, 0>(smem, s, cq, f, w9, c9, nullptr, nullptr, dw, i, L, dvec);
    else if (wid == 1)
      run_role<7, 1>(smem, s, cq, f, w7, c7, w1, c1, dw, i, L, dvec);
    else
      run_role<5, 3>(smem, s, cq, f, w5, c5, w3, c3, dw, i, L, dvec);
  }

  // reduce dot partials over 3 waves x 16 filters  (D row = (lane>>4)*4 + r)
  __syncthreads();
  float* red = (float*)smem;
  *(f32x4*)&red[(wid * 64 + lane) * 4] = dvec;
  __syncthreads();
  if (tid < 16) {
    float sum = 0.f;
    const int g4 = tid >> 2, r = tid & 3;
    for (int w = 0; w < 3; ++w)
      #pragma unroll
      for (int f2 = 0; f2 < 16; ++f2)
        sum += red[(w * 64 + g4 * 16 + f2) * 4 + r];
    part[h * B + b0 + tid] = sum;    // pre-sigmoid partial (no db)
  }
}

__global__ void combine_sigmoid(const float* __restrict__ part,
                                const float* __restrict__ db,
                                float* __restrict__ out)
{
  const int i = blockIdx.x * blockDim.x + threadIdx.x;
  if (i < B) {
    const float sum = part[i] + part[B + i] + db[0];
    out[i] = 1.0f / (1.0f + expf(-sum));
  }
}

} // namespace

extern "C" void kernel_launch(void* const* d_in, const int* in_sizes, int n_in,
                              void* d_out, int out_size, void* d_ws, size_t ws_size,
                              hipStream_t stream) {
  (void)ws_size; (void)out_size;
  const float* xs[7];
  for (int i = 0; i < 7; ++i) xs[i] = (const float*)d_in[i];

  const float* wptr[5] = {nullptr, nullptr, nullptr, nullptr, nullptr};
  const float* cptr[5] = {nullptr, nullptr, nullptr, nullptr, nullptr};
  const float* dw = nullptr;
  const float* db = nullptr;
  int c_seen = 0;
  for (int idx = 7; idx < n_in; ++idx) {
    const int sz = in_sizes[idx];
    const float* p = (const float*)d_in[idx];
    if (sz == 1) { db = p; }
    else if (sz == 16 * 35) { dw = p; }                 // 560
    else if (sz == 7 * 16) { cptr[c_seen++] = p; }      // 112, appear in k order
    else {
      const int k = sz / (7 * 16 * 32);                 // 1,3,5,7,9
      wptr[(k - 1) / 2] = p;
    }
  }

  float* part = (float*)d_ws;   // 2*B floats = 128 KB (only per-block partials)

  dim3 grid(2 * (B / NS)), block(NT);
  hipLaunchKernelGGL(nettcr_mfma, grid, block, 0, stream,
                     xs[0], xs[1], xs[2], xs[3], xs[4], xs[5], xs[6],
                     wptr[0], cptr[0], wptr[1], cptr[1], wptr[2], cptr[2],
                     wptr[3], cptr[3], wptr[4], cptr[4], dw, part);

  hipLaunchKernelGGL(combine_sigmoid, dim3((B + 255) / 256), dim3(256), 0, stream,
                     part, db, (float*)d_out);
}

// Round 9
// 118.828 us; speedup vs baseline: 1.9047x; 1.5579x over previous
//
#include <hip/hip_runtime.h>
#include <cmath>

namespace {

using bf16x8 = __attribute__((ext_vector_type(8))) short;
using f32x4  = __attribute__((ext_vector_type(4))) float;

constexpr int NT = 192;        // 3 waves per block
constexpr int NS = 16;         // samples per block (one MFMA M-tile)
constexpr int TILE_BYTES = NS * 31 * 32 * 2;  // 31744 B (LPAD=31)
constexpr int B = 16384;

__device__ __forceinline__ short f2bf(float f) {  // RNE float->bf16
  unsigned u = __float_as_uint(f);
  return (short)((u + 0x7FFFu + ((u >> 16) & 1u)) >> 16);
}

// Granule index for tile[s][q][cq*8..+7]. Bijective: only permutes cq within
// the (s,q) quad (blocks 4u..4u+3 disjoint). Proven correct+fast in round 3.
__device__ __forceinline__ int gidx(int s, int q, int cq) {
  return (s * 31 + q) * 4 + ((cq ^ ((s >> 1) + (q >> 1))) & 3);
}

__device__ __forceinline__ bf16x8 ldcol(const char* smem, int s, int cq, int q) {
  return *(const bf16x8*)(smem + (gidx(s, q, cq) << 4));
}

// One wave-role: kernel sizes K1 (and optional nested K2 < K1). Runtime i,L.
// 2 accumulator chains (r3-proven): keeps the live set ~100 VGPR so the
// 128-register cap below is spill-free.
template<int K1, int K2>
__device__ __forceinline__ void run_role(
    const char* __restrict__ smem, int s, int cq, int f,
    const float* __restrict__ wk1, const float* __restrict__ ck1,
    const float* __restrict__ wk2, const float* __restrict__ ck2,
    const float* __restrict__ dw, int i, int L, f32x4& dvec)
{
  constexpr int KK1 = (K1 - 1) / 2;
  constexpr int KK2 = (K2 > 0) ? (K2 - 1) / 2 : 0;

  // B-operand fragments: lane = filter f, holds w[f][cq*8+j][t], j=0..7.
  bf16x8 wf1[K1];
  #pragma unroll
  for (int t = 0; t < K1; ++t) {
    const float* wp = wk1 + (size_t)((i * 16 + f) * 32 + cq * 8) * K1 + t;
    bf16x8 v;
    #pragma unroll
    for (int j = 0; j < 8; ++j) v[j] = f2bf(wp[(size_t)j * K1]);
    wf1[t] = v;
  }
  bf16x8 wf2[(K2 > 0) ? K2 : 1];
  if constexpr (K2 > 0) {
    #pragma unroll
    for (int t = 0; t < K2; ++t) {
      const float* wp = wk2 + (size_t)((i * 16 + f) * 32 + cq * 8) * K2 + t;
      bf16x8 v;
      #pragma unroll
      for (int j = 0; j < 8; ++j) v[j] = f2bf(wp[(size_t)j * K2]);
      wf2[t] = v;
    }
  }

  const float b1 = ck1[i * 16 + f];
  float b2 = 0.f;
  if constexpr (K2 > 0) b2 = ck2[i * 16 + f];

  f32x4 mx1 = {0.f, 0.f, 0.f, 0.f};   // ReLU folded into max-init 0
  f32x4 mx2 = {0.f, 0.f, 0.f, 0.f};

  // Sliding window invariant: af[(P+t)%K1] holds padded col P + 4 - KK1 + t.
  bf16x8 af[K1];
  #pragma unroll
  for (int j = 0; j < K1; ++j) af[j] = ldcol(smem, s, cq, 4 - KK1 + j);

  auto body = [&](int p, int pi) {
    f32x4 aa = {b1, b1, b1, b1};      // even-tap chain (bias pre-added)
    f32x4 ab = {0.f, 0.f, 0.f, 0.f};  // odd-tap chain (ILP split)
    #pragma unroll
    for (int t = 0; t < K1; ++t) {
      if (t & 1)
        ab = __builtin_amdgcn_mfma_f32_16x16x32_bf16(af[(pi + t) % K1], wf1[t], ab, 0, 0, 0);
      else
        aa = __builtin_amdgcn_mfma_f32_16x16x32_bf16(af[(pi + t) % K1], wf1[t], aa, 0, 0, 0);
    }
    if constexpr (K2 > 0) {
      f32x4 ac = {b2, b2, b2, b2};
      #pragma unroll
      for (int t = 0; t < K2; ++t)
        ac = __builtin_amdgcn_mfma_f32_16x16x32_bf16(af[(pi + (KK1 - KK2) + t) % K1], wf2[t], ac, 0, 0, 0);
      #pragma unroll
      for (int r = 0; r < 4; ++r) mx2[r] = fmaxf(mx2[r], ac[r]);
    }
    #pragma unroll
    for (int r = 0; r < 4; ++r) mx1[r] = fmaxf(mx1[r], aa[r] + ab[r]);
    if (p + pi + 1 < L)                         // slide: col for position p+pi+1
      af[pi] = ldcol(smem, s, cq, p + pi + 5 + KK1);
  };

  int p = 0;
  for (; p + K1 <= L; p += K1) {                // K1-blocked -> static rotation idx
    #pragma unroll
    for (int pi = 0; pi < K1; ++pi) body(p, pi);
  }
  #pragma unroll
  for (int pi = 0; pi < K1 - 1; ++pi)           // tail (rem <= K1-1)
    if (p + pi < L) body(p, pi);

  {
    const float dv1 = dw[(i * 5 + KK1) * 16 + f];
    #pragma unroll
    for (int r = 0; r < 4; ++r) dvec[r] = fmaf(mx1[r], dv1, dvec[r]);
  }
  if constexpr (K2 > 0) {
    const float dv2 = dw[(i * 5 + KK2) * 16 + f];
    #pragma unroll
    for (int r = 0; r < 4; ++r) dvec[r] = fmaf(mx2[r], dv2, dvec[r]);
  }
}

// ---- main: grid 2048; blockIdx = tile*2 + half; half 0 -> inputs {0,3,5},
// half 1 -> {1,2,4,6}; pre-sigmoid partial dot written to ws.
// launch_bounds 2nd arg, measured on this toolchain: cap = 512/(2*arg).
// arg3 -> 84 (spilled), arg4 -> 64 (spilled hard), none -> 184 (2 waves/SIMD,
// occupancy 8%). arg2 -> 128 = the 4-waves/SIMD tier, fits ~100-reg live set.
__global__ __launch_bounds__(NT, 2) void nettcr_mfma(
    const float* __restrict__ x0, const float* __restrict__ x1,
    const float* __restrict__ x2, const float* __restrict__ x3,
    const float* __restrict__ x4, const float* __restrict__ x5,
    const float* __restrict__ x6,
    const float* __restrict__ w1, const float* __restrict__ c1,
    const float* __restrict__ w3, const float* __restrict__ c3,
    const float* __restrict__ w5, const float* __restrict__ c5,
    const float* __restrict__ w7, const float* __restrict__ c7,
    const float* __restrict__ w9, const float* __restrict__ c9,
    const float* __restrict__ dw,
    float* __restrict__ part)
{
  __shared__ __align__(16) char smem[TILE_BYTES];
  const int tid  = threadIdx.x;
  const int lane = tid & 63;
  const int wid  = tid >> 6;
  const int h    = blockIdx.x & 1;
  const int b0   = (blockIdx.x >> 1) * NS;
  const int s    = lane & 15;      // A-side: sample row
  const int cq   = lane >> 4;      // k-quadrant: channels cq*8..+7
  const int f    = lane & 15;      // B-side: filter col

  f32x4 dvec = {0.f, 0.f, 0.f, 0.f};

  const int nin = h ? 4 : 3;
  for (int j = 0; j < nin; ++j) {
    const float* xi; int i, L;
    if (h == 0) {
      switch (j) {
        case 0:  i = 0; xi = x0; L = 12; break;
        case 1:  i = 3; xi = x3; L = 22; break;
        default: i = 5; xi = x5; L = 7;  break;
      }
    } else {
      switch (j) {
        case 0:  i = 1; xi = x1; L = 7;  break;
        case 1:  i = 2; xi = x2; L = 8;  break;
        case 2:  i = 4; xi = x4; L = 6;  break;
        default: i = 6; xi = x6; L = 23; break;
      }
    }
    __syncthreads();   // all waves done reading previous tile
    // stage: x[b0+ss][c][l] (f32) -> tile[ss][l+4][c] (bf16), swizzled writes
    for (int e = tid; e < 64 * L; e += NT) {
      const int l  = e % L;
      const int rr = e / L;
      const int cg = rr & 3;
      const int ss = rr >> 2;
      const float* src = xi + ((size_t)(b0 + ss) * 32 + cg * 8) * L + l;
      bf16x8 pk;
      #pragma unroll
      for (int jj = 0; jj < 8; ++jj) pk[jj] = f2bf(src[(size_t)jj * L]);
      *(bf16x8*)(smem + (gidx(ss, l + 4, cg) << 4)) = pk;
    }
    // zero the 4+4 SAME-padding columns (branchless taps)
    for (int e = tid; e < 512; e += NT) {
      const int q8 = e & 7;
      const int q  = (q8 < 4) ? q8 : (L + q8);
      const int cg = (e >> 3) & 3;
      const int ss = e >> 5;
      bf16x8 z = {0, 0, 0, 0, 0, 0, 0, 0};
      *(bf16x8*)(smem + (gidx(ss, q, cg) << 4)) = z;
    }
    __syncthreads();   // tile ready

    if (wid == 0)
      run_role<9, 0>(smem, s, cq, f, w9, c9, nullptr, nullptr, dw, i, L, dvec);
    else if (wid == 1)
      run_role<7, 1>(smem, s, cq, f, w7, c7, w1, c1, dw, i, L, dvec);
    else
      run_role<5, 3>(smem, s, cq, f, w5, c5, w3, c3, dw, i, L, dvec);
  }

  // reduce dot partials over 3 waves x 16 filters  (D row = (lane>>4)*4 + r)
  __syncthreads();
  float* red = (float*)smem;
  *(f32x4*)&red[(wid * 64 + lane) * 4] = dvec;
  __syncthreads();
  if (tid < 16) {
    float sum = 0.f;
    const int g4 = tid >> 2, r = tid & 3;
    for (int w = 0; w < 3; ++w)
      #pragma unroll
      for (int f2 = 0; f2 < 16; ++f2)
        sum += red[(w * 64 + g4 * 16 + f2) * 4 + r];
    part[h * B + b0 + tid] = sum;    // pre-sigmoid partial (no db)
  }
}

__global__ void combine_sigmoid(const float* __restrict__ part,
                                const float* __restrict__ db,
                                float* __restrict__ out)
{
  const int i = blockIdx.x * blockDim.x + threadIdx.x;
  if (i < B) {
    const float sum = part[i] + part[B + i] + db[0];
    out[i] = 1.0f / (1.0f + expf(-sum));
  }
}

} // namespace

extern "C" void kernel_launch(void* const* d_in, const int* in_sizes, int n_in,
                              void* d_out, int out_size, void* d_ws, size_t ws_size,
                              hipStream_t stream) {
  (void)ws_size; (void)out_size;
  const float* xs[7];
  for (int i = 0; i < 7; ++i) xs[i] = (const float*)d_in[i];

  const float* wptr[5] = {nullptr, nullptr, nullptr, nullptr, nullptr};
  const float* cptr[5] = {nullptr, nullptr, nullptr, nullptr, nullptr};
  const float* dw = nullptr;
  const float* db = nullptr;
  int c_seen = 0;
  for (int idx = 7; idx < n_in; ++idx) {
    const int sz = in_sizes[idx];
    const float* p = (const float*)d_in[idx];
    if (sz == 1) { db = p; }
    else if (sz == 16 * 35) { dw = p; }                 // 560
    else if (sz == 7 * 16) { cptr[c_seen++] = p; }      // 112, appear in k order
    else {
      const int k = sz / (7 * 16 * 32);                 // 1,3,5,7,9
      wptr[(k - 1) / 2] = p;
    }
  }

  float* part = (float*)d_ws;   // 2*B floats = 128 KB (only per-block partials)

  dim3 grid(2 * (B / NS)), block(NT);
  hipLaunchKernelGGL(nettcr_mfma, grid, block, 0, stream,
                     xs[0], xs[1], xs[2], xs[3], xs[4], xs[5], xs[6],
                     wptr[0], cptr[0], wptr[1], cptr[1], wptr[2], cptr[2],
                     wptr[3], cptr[3], wptr[4], cptr[4], dw, part);

  hipLaunchKernelGGL(combine_sigmoid, dim3((B + 255) / 256), dim3(256), 0, stream,
                     part, db, (float*)d_out);
}

// Round 10
// 113.170 us; speedup vs baseline: 1.9999x; 1.0500x over previous
//
#include <hip/hip_runtime.h>
#include <cmath>

namespace {

using bf16x8 = __attribute__((ext_vector_type(8))) short;
using f32x4  = __attribute__((ext_vector_type(4))) float;

constexpr int NT = 192;        // 3 waves per block
constexpr int NS = 16;         // samples per block (one MFMA M-tile)
constexpr int TILE_BYTES = NS * 31 * 32 * 2;  // 31744 B (LPAD=31)
constexpr int B = 16384;
constexpr int NTILE = B / NS;  // 1024 sample tiles

__device__ __forceinline__ short f2bf(float f) {  // RNE float->bf16
  unsigned u = __float_as_uint(f);
  return (short)((u + 0x7FFFu + ((u >> 16) & 1u)) >> 16);
}

// Granule index for tile[s][q][cq*8..+7]. Bijective: only permutes cq within
// the (s,q) quad (blocks 4u..4u+3 disjoint). Proven correct+fast in round 3.
__device__ __forceinline__ int gidx(int s, int q, int cq) {
  return (s * 31 + q) * 4 + ((cq ^ ((s >> 1) + (q >> 1))) & 3);
}

__device__ __forceinline__ bf16x8 ldcol(const char* smem, int s, int cq, int q) {
  return *(const bf16x8*)(smem + (gidx(s, q, cq) << 4));
}

// One wave-role: kernel sizes K1 (and optional nested K2 < K1). Runtime i,L.
// 2 accumulator chains; live set ~100 VGPR -> spill-free under the 128 cap.
template<int K1, int K2>
__device__ __forceinline__ void run_role(
    const char* __restrict__ smem, int s, int cq, int f,
    const float* __restrict__ wk1, const float* __restrict__ ck1,
    const float* __restrict__ wk2, const float* __restrict__ ck2,
    const float* __restrict__ dw, int i, int L, f32x4& dvec)
{
  constexpr int KK1 = (K1 - 1) / 2;
  constexpr int KK2 = (K2 > 0) ? (K2 - 1) / 2 : 0;

  // B-operand fragments: lane = filter f, holds w[f][cq*8+j][t], j=0..7.
  bf16x8 wf1[K1];
  #pragma unroll
  for (int t = 0; t < K1; ++t) {
    const float* wp = wk1 + (size_t)((i * 16 + f) * 32 + cq * 8) * K1 + t;
    bf16x8 v;
    #pragma unroll
    for (int j = 0; j < 8; ++j) v[j] = f2bf(wp[(size_t)j * K1]);
    wf1[t] = v;
  }
  bf16x8 wf2[(K2 > 0) ? K2 : 1];
  if constexpr (K2 > 0) {
    #pragma unroll
    for (int t = 0; t < K2; ++t) {
      const float* wp = wk2 + (size_t)((i * 16 + f) * 32 + cq * 8) * K2 + t;
      bf16x8 v;
      #pragma unroll
      for (int j = 0; j < 8; ++j) v[j] = f2bf(wp[(size_t)j * K2]);
      wf2[t] = v;
    }
  }

  const float b1 = ck1[i * 16 + f];
  float b2 = 0.f;
  if constexpr (K2 > 0) b2 = ck2[i * 16 + f];

  f32x4 mx1 = {0.f, 0.f, 0.f, 0.f};   // ReLU folded into max-init 0
  f32x4 mx2 = {0.f, 0.f, 0.f, 0.f};

  // Sliding window invariant: af[(P+t)%K1] holds padded col P + 4 - KK1 + t.
  bf16x8 af[K1];
  #pragma unroll
  for (int j = 0; j < K1; ++j) af[j] = ldcol(smem, s, cq, 4 - KK1 + j);

  auto body = [&](int p, int pi) {
    f32x4 aa = {b1, b1, b1, b1};      // even-tap chain (bias pre-added)
    f32x4 ab = {0.f, 0.f, 0.f, 0.f};  // odd-tap chain (ILP split)
    #pragma unroll
    for (int t = 0; t < K1; ++t) {
      if (t & 1)
        ab = __builtin_amdgcn_mfma_f32_16x16x32_bf16(af[(pi + t) % K1], wf1[t], ab, 0, 0, 0);
      else
        aa = __builtin_amdgcn_mfma_f32_16x16x32_bf16(af[(pi + t) % K1], wf1[t], aa, 0, 0, 0);
    }
    if constexpr (K2 > 0) {
      f32x4 ac = {b2, b2, b2, b2};
      #pragma unroll
      for (int t = 0; t < K2; ++t)
        ac = __builtin_amdgcn_mfma_f32_16x16x32_bf16(af[(pi + (KK1 - KK2) + t) % K1], wf2[t], ac, 0, 0, 0);
      #pragma unroll
      for (int r = 0; r < 4; ++r) mx2[r] = fmaxf(mx2[r], ac[r]);
    }
    #pragma unroll
    for (int r = 0; r < 4; ++r) mx1[r] = fmaxf(mx1[r], aa[r] + ab[r]);
    if (p + pi + 1 < L)                         // slide: col for position p+pi+1
      af[pi] = ldcol(smem, s, cq, p + pi + 5 + KK1);
  };

  __builtin_amdgcn_s_setprio(1);   // favor MFMA-issuing waves over staging waves
  int p = 0;
  for (; p + K1 <= L; p += K1) {                // K1-blocked -> static rotation idx
    #pragma unroll
    for (int pi = 0; pi < K1; ++pi) body(p, pi);
  }
  #pragma unroll
  for (int pi = 0; pi < K1 - 1; ++pi)           // tail (rem <= K1-1)
    if (p + pi < L) body(p, pi);
  __builtin_amdgcn_s_setprio(0);

  {
    const float dv1 = dw[(i * 5 + KK1) * 16 + f];
    #pragma unroll
    for (int r = 0; r < 4; ++r) dvec[r] = fmaf(mx1[r], dv1, dvec[r]);
  }
  if constexpr (K2 > 0) {
    const float dv2 = dw[(i * 5 + KK2) * 16 + f];
    #pragma unroll
    for (int r = 0; r < 4; ++r) dvec[r] = fmaf(mx2[r], dv2, dvec[r]);
  }
}

// ---- main: grid 7168 = 7 inputs x 1024 tiles. One input per block: a single
// stage->barrier->compute phase; resident blocks mix inputs/roles so staging
// of one block hides under MFMA of another. Partial dot -> part[i*B + b].
__global__ __launch_bounds__(NT, 2) void nettcr_mfma(
    const float* __restrict__ x0, const float* __restrict__ x1,
    const float* __restrict__ x2, const float* __restrict__ x3,
    const float* __restrict__ x4, const float* __restrict__ x5,
    const float* __restrict__ x6,
    const float* __restrict__ w1, const float* __restrict__ c1,
    const float* __restrict__ w3, const float* __restrict__ c3,
    const float* __restrict__ w5, const float* __restrict__ c5,
    const float* __restrict__ w7, const float* __restrict__ c7,
    const float* __restrict__ w9, const float* __restrict__ c9,
    const float* __restrict__ dw,
    float* __restrict__ part)
{
  __shared__ __align__(16) char smem[TILE_BYTES];
  const int tid  = threadIdx.x;
  const int lane = tid & 63;
  const int wid  = tid >> 6;
  const int bx   = blockIdx.x;
  const int i    = bx % 7;             // input id (mixes inputs across CUs)
  const int b0   = (bx / 7) * NS;      // sample tile
  const int s    = lane & 15;      // A-side: sample row
  const int cq   = lane >> 4;      // k-quadrant: channels cq*8..+7
  const int f    = lane & 15;      // B-side: filter col

  const float* xi; int L;
  switch (i) {
    case 0: xi = x0; L = 12; break;
    case 1: xi = x1; L = 7;  break;
    case 2: xi = x2; L = 8;  break;
    case 3: xi = x3; L = 22; break;
    case 4: xi = x4; L = 6;  break;
    case 5: xi = x5; L = 7;  break;
    default: xi = x6; L = 23; break;
  }

  // stage: x[b0+ss][c][l] (f32) -> tile[ss][l+4][c] (bf16), swizzled writes
  for (int e = tid; e < 64 * L; e += NT) {
    const int l  = e % L;
    const int rr = e / L;
    const int cg = rr & 3;
    const int ss = rr >> 2;
    const float* src = xi + ((size_t)(b0 + ss) * 32 + cg * 8) * L + l;
    bf16x8 pk;
    #pragma unroll
    for (int jj = 0; jj < 8; ++jj) pk[jj] = f2bf(src[(size_t)jj * L]);
    *(bf16x8*)(smem + (gidx(ss, l + 4, cg) << 4)) = pk;
  }
  // zero the 4+4 SAME-padding columns (branchless taps)
  for (int e = tid; e < 512; e += NT) {
    const int q8 = e & 7;
    const int q  = (q8 < 4) ? q8 : (L + q8);
    const int cg = (e >> 3) & 3;
    const int ss = e >> 5;
    bf16x8 z = {0, 0, 0, 0, 0, 0, 0, 0};
    *(bf16x8*)(smem + (gidx(ss, q, cg) << 4)) = z;
  }
  __syncthreads();   // tile ready

  f32x4 dvec = {0.f, 0.f, 0.f, 0.f};
  if (wid == 0)
    run_role<9, 0>(smem, s, cq, f, w9, c9, nullptr, nullptr, dw, i, L, dvec);
  else if (wid == 1)
    run_role<7, 1>(smem, s, cq, f, w7, c7, w1, c1, dw, i, L, dvec);
  else
    run_role<5, 3>(smem, s, cq, f, w5, c5, w3, c3, dw, i, L, dvec);

  // reduce dot partials over 3 waves x 16 filters  (D row = (lane>>4)*4 + r)
  __syncthreads();   // done reading tile; reuse smem for reduction
  float* red = (float*)smem;
  *(f32x4*)&red[(wid * 64 + lane) * 4] = dvec;
  __syncthreads();
  if (tid < 16) {
    float sum = 0.f;
    const int g4 = tid >> 2, r = tid & 3;
    for (int w = 0; w < 3; ++w)
      #pragma unroll
      for (int f2 = 0; f2 < 16; ++f2)
        sum += red[(w * 64 + g4 * 16 + f2) * 4 + r];
    part[i * B + b0 + tid] = sum;    // pre-sigmoid partial (no db)
  }
}

__global__ void combine_sigmoid(const float* __restrict__ part,
                                const float* __restrict__ db,
                                float* __restrict__ out)
{
  const int i = blockIdx.x * blockDim.x + threadIdx.x;
  if (i < B) {
    float sum = db[0];
    #pragma unroll
    for (int j = 0; j < 7; ++j) sum += part[j * B + i];
    out[i] = 1.0f / (1.0f + expf(-sum));
  }
}

} // namespace

extern "C" void kernel_launch(void* const* d_in, const int* in_sizes, int n_in,
                              void* d_out, int out_size, void* d_ws, size_t ws_size,
                              hipStream_t stream) {
  (void)ws_size; (void)out_size;
  const float* xs[7];
  for (int i = 0; i < 7; ++i) xs[i] = (const float*)d_in[i];

  const float* wptr[5] = {nullptr, nullptr, nullptr, nullptr, nullptr};
  const float* cptr[5] = {nullptr, nullptr, nullptr, nullptr, nullptr};
  const float* dw = nullptr;
  const float* db = nullptr;
  int c_seen = 0;
  for (int idx = 7; idx < n_in; ++idx) {
    const int sz = in_sizes[idx];
    const float* p = (const float*)d_in[idx];
    if (sz == 1) { db = p; }
    else if (sz == 16 * 35) { dw = p; }                 // 560
    else if (sz == 7 * 16) { cptr[c_seen++] = p; }      // 112, appear in k order
    else {
      const int k = sz / (7 * 16 * 32);                 // 1,3,5,7,9
      wptr[(k - 1) / 2] = p;
    }
  }

  float* part = (float*)d_ws;   // 7*B floats = 458 KB (per-block partials)

  dim3 grid(7 * NTILE), block(NT);
  hipLaunchKernelGGL(nettcr_mfma, grid, block, 0, stream,
                     xs[0], xs[1], xs[2], xs[3], xs[4], xs[5], xs[6],
                     wptr[0], cptr[0], wptr[1], cptr[1], wptr[2], cptr[2],
                     wptr[3], cptr[3], wptr[4], cptr[4], dw, part);

  hipLaunchKernelGGL(combine_sigmoid, dim3((B + 255) / 256), dim3(256), 0, stream,
                     part, db, (float*)d_out);
}